// Round 5
// baseline (176.327 us; speedup 1.0000x reference)
//
#include <hip/hip_runtime.h>
#include <math.h>

#define CB 8
#define CNX 512
#define CNR 512
#define CD 256
#define CH 256

__device__ __forceinline__ float fast_rcp(float x) {
#if __has_builtin(__builtin_amdgcn_rcpf)
  return __builtin_amdgcn_rcpf(x);
#else
  return 1.0f / x;
#endif
}
__device__ __forceinline__ float fast_exp2(float x) {
#if __has_builtin(__builtin_amdgcn_exp2f)
  return __builtin_amdgcn_exp2f(x);
#else
  return exp2f(x);
#endif
}

// Fused projections: z=0 -> exp(2*(X@W_X^T+b_X))^T, z=1 -> same for ref.
// ET[b][h][x] = exp2(K2L*(sum_k A[m][k]*W[h][k] + bias[h])), m=b*512+x
// 64(m) x 64(h) tile, K-tile 16, grid (64,4,2), block 256, 4x4 microtile
__global__ __launch_bounds__(256) void proj_fused(
    const float* __restrict__ A0, const float* __restrict__ A1,
    const float* __restrict__ W0, const float* __restrict__ W1,
    const float* __restrict__ bias0, const float* __restrict__ bias1,
    float* __restrict__ E0, float* __restrict__ E1) {
  __shared__ float As[16][68];  // [k][m] padded
  __shared__ float Ws[16][68];  // [k][h] padded
  const int K = CD;
  int z = blockIdx.z;
  const float* A = z ? A1 : A0;
  const float* W = z ? W1 : W0;
  const float* bias = z ? bias1 : bias0;
  float* ET = z ? E1 : E0;
  int m0 = blockIdx.x * 64, n0 = blockIdx.y * 64;
  int tid = threadIdx.x;
  int tx = tid & 15, ty = tid >> 4;  // tx -> h, ty -> m(x)
  int lrow = tid >> 2, lc4 = tid & 3;
  float acc[4][4] = {};
  const float* pA = A + (size_t)(m0 + lrow) * K + lc4 * 4;
  const float* pW = W + (size_t)(n0 + lrow) * K + lc4 * 4;
  for (int kt = 0; kt < K; kt += 16) {
    float4 av = *(const float4*)(pA + kt);
    float4 wv = *(const float4*)(pW + kt);
    __syncthreads();
    As[lc4 * 4 + 0][lrow] = av.x;
    As[lc4 * 4 + 1][lrow] = av.y;
    As[lc4 * 4 + 2][lrow] = av.z;
    As[lc4 * 4 + 3][lrow] = av.w;
    Ws[lc4 * 4 + 0][lrow] = wv.x;
    Ws[lc4 * 4 + 1][lrow] = wv.y;
    Ws[lc4 * 4 + 2][lrow] = wv.z;
    Ws[lc4 * 4 + 3][lrow] = wv.w;
    __syncthreads();
#pragma unroll
    for (int k = 0; k < 16; k++) {
      float4 a4 = *(const float4*)&As[k][ty * 4];
      float4 w4 = *(const float4*)&Ws[k][tx * 4];
      float am[4] = {a4.x, a4.y, a4.z, a4.w};
      float wm[4] = {w4.x, w4.y, w4.z, w4.w};
#pragma unroll
      for (int i = 0; i < 4; i++)
#pragma unroll
        for (int j = 0; j < 4; j++)
          acc[i][j] = fmaf(am[i], wm[j], acc[i][j]);
    }
  }
  const float K2L = 2.8853900817779268f;  // 2*log2(e)
  float4 bv = *(const float4*)(bias + n0 + tx * 4);
  float bm[4] = {bv.x, bv.y, bv.z, bv.w};
  int b = m0 >> 9;
  int xbase = (m0 & 511) + ty * 4;
#pragma unroll
  for (int j = 0; j < 4; j++) {
    int h = n0 + tx * 4 + j;
    float4 o = {fast_exp2(K2L * (acc[0][j] + bm[j])),
                fast_exp2(K2L * (acc[1][j] + bm[j])),
                fast_exp2(K2L * (acc[2][j] + bm[j])),
                fast_exp2(K2L * (acc[3][j] + bm[j]))};
    *(float4*)(ET + ((size_t)b * CH + h) * CNX + xbase) = o;
  }
}

// eT[b][r][x] = exp(-2 * sum_h v_w[h] / (exT[b][h][x]*erT[b][h][r] + 1))
// (unnormalized attention weight; softmax constant drops, normalization
//  happens in wsum_fused)
// 4-way h-merge; 64(x) x 32(r) tile, grid (8,16,8)=1024, block 256
// microtile: tx->x (4), ty->r (2); b128 x-fragment reads
__global__ __launch_bounds__(256) void scores_kernel(
    const float* __restrict__ exT, const float* __restrict__ erT,
    const float* __restrict__ v_w, float* __restrict__ eT) {
  __shared__ float xs[64][64];  // [h][x] 16 KB
  __shared__ float rs[64][32];  // [h][r] 8 KB
  __shared__ float vsh[CH];
  int b = blockIdx.z;
  int x0 = blockIdx.x * 64, r0 = blockIdx.y * 32;
  int tid = threadIdx.x;
  int tx = tid & 15, ty = tid >> 4;
  vsh[tid] = v_w[tid];
  float acc[2][4] = {};
  const float* pX = exT + (size_t)b * CH * CNX + x0;
  const float* pR = erT + (size_t)b * CH * CNR + r0;
  int xrow = tid >> 4, xc4 = tid & 15;  // 16 h-rows x 16 float4 per pass
  int rrow = tid >> 3, rc4 = tid & 7;   // 32 h-rows x 8 float4 per pass
  for (int hc = 0; hc < CH; hc += 64) {
    float4 xv[4], rv[2];
#pragma unroll
    for (int p = 0; p < 4; p++)
      xv[p] = *(const float4*)(pX + (size_t)(hc + xrow + p * 16) * CNX + xc4 * 4);
#pragma unroll
    for (int p = 0; p < 2; p++)
      rv[p] = *(const float4*)(pR + (size_t)(hc + rrow + p * 32) * CNR + rc4 * 4);
    __syncthreads();
#pragma unroll
    for (int p = 0; p < 4; p++)
      *(float4*)&xs[xrow + p * 16][xc4 * 4] = xv[p];
#pragma unroll
    for (int p = 0; p < 2; p++)
      *(float4*)&rs[rrow + p * 32][rc4 * 4] = rv[p];
    __syncthreads();
#pragma unroll 4
    for (int hq = 0; hq < 16; hq++) {
      int h0 = hq * 4;
      float4 vv = *(const float4*)&vsh[hc + h0];
      float4 xa = *(const float4*)&xs[h0 + 0][tx * 4];
      float4 xb = *(const float4*)&xs[h0 + 1][tx * 4];
      float4 xc = *(const float4*)&xs[h0 + 2][tx * 4];
      float4 xd = *(const float4*)&xs[h0 + 3][tx * 4];
      float2 ra = *(const float2*)&rs[h0 + 0][ty * 2];
      float2 rb = *(const float2*)&rs[h0 + 1][ty * 2];
      float2 rc = *(const float2*)&rs[h0 + 2][ty * 2];
      float2 rd = *(const float2*)&rs[h0 + 3][ty * 2];
      float xam[4] = {xa.x, xa.y, xa.z, xa.w};
      float xbm[4] = {xb.x, xb.y, xb.z, xb.w};
      float xcm[4] = {xc.x, xc.y, xc.z, xc.w};
      float xdm[4] = {xd.x, xd.y, xd.z, xd.w};
      float ram[2] = {ra.x, ra.y};
      float rbm[2] = {rb.x, rb.y};
      float rcm[2] = {rc.x, rc.y};
      float rdm[2] = {rd.x, rd.y};
#pragma unroll
      for (int i = 0; i < 2; i++)
#pragma unroll
        for (int j = 0; j < 4; j++) {
          float a = fmaf(ram[i], xam[j], 1.0f);
          float bb = fmaf(rbm[i], xbm[j], 1.0f);
          float c = fmaf(rcm[i], xcm[j], 1.0f);
          float d = fmaf(rdm[i], xdm[j], 1.0f);
          float q12 = a * bb, q34 = c * d;
          float p12 = fmaf(vv.y, a, vv.x * bb);
          float p34 = fmaf(vv.w, c, vv.z * d);
          float num = fmaf(p34, q12, p12 * q34);
          acc[i][j] = fmaf(num, fast_rcp(q12 * q34), acc[i][j]);
        }
    }
  }
  // e = exp(-2 * acc); exp2 with fused scale
  const float NL2E = -2.0f * 1.4426950408889634f;
  float* pO = eT + ((size_t)b * CNR + r0 + ty * 2) * CNX + x0 + tx * 4;
#pragma unroll
  for (int i = 0; i < 2; i++) {
    float4 o = {fast_exp2(acc[i][0] * NL2E), fast_exp2(acc[i][1] * NL2E),
                fast_exp2(acc[i][2] * NL2E), fast_exp2(acc[i][3] * NL2E)};
    *(float4*)(pO + (size_t)i * CNX) = o;
  }
}

// Normalized weighted sum from unnormalized weights eT:
// out[b][r][d] = sum_x eT[b][r][x]*X[b][x][d] / sum_x eT[b][r][x]
// 32(r) x 64(d) tile, K-tile 32, grid (16,4,8)=512 blocks
__global__ __launch_bounds__(256) void wsum_fused(
    const float* __restrict__ eT, const float* __restrict__ X,
    float* __restrict__ out) {
  __shared__ float As[32][34];  // [k][r] unnormalized attn (even pad for b64)
  __shared__ float Bs[32][68];  // [k][d]
  __shared__ float dn[32];
  int b = blockIdx.z;
  int r0 = blockIdx.x * 32, d0 = blockIdx.y * 64;
  int tid = threadIdx.x;
  int tx = tid & 15, ty = tid >> 4;    // tx -> d(4), ty -> r(2)
  int arow = tid >> 3, ak4 = tid & 7;  // eT: 32 r-rows x 8 float4
  int brow = tid >> 4, bc4 = tid & 15; // X: 16 x-rows x 64 d (2 passes)
  float acc[2][4] = {};
  float dsum = 0.0f;
  for (int kt = 0; kt < CNX; kt += 32) {
    float4 ev = *(const float4*)(eT + ((size_t)b * CNR + r0 + arow) * CNX + kt + ak4 * 4);
    dsum += (ev.x + ev.y) + (ev.z + ev.w);
    float4 bv0 = *(const float4*)(X + ((size_t)b * CNX + kt + brow) * CD + d0 + bc4 * 4);
    float4 bv1 = *(const float4*)(X + ((size_t)b * CNX + kt + brow + 16) * CD + d0 + bc4 * 4);
    __syncthreads();
    As[ak4 * 4 + 0][arow] = ev.x;
    As[ak4 * 4 + 1][arow] = ev.y;
    As[ak4 * 4 + 2][arow] = ev.z;
    As[ak4 * 4 + 3][arow] = ev.w;
    *(float4*)&Bs[brow][bc4 * 4] = bv0;
    *(float4*)&Bs[brow + 16][bc4 * 4] = bv1;
    __syncthreads();
#pragma unroll 8
    for (int k = 0; k < 32; k++) {
      float2 a2 = *(const float2*)&As[k][ty * 2];
      float4 b4 = *(const float4*)&Bs[k][tx * 4];
      float bm[4] = {b4.x, b4.y, b4.z, b4.w};
#pragma unroll
      for (int j = 0; j < 4; j++) {
        acc[0][j] = fmaf(a2.x, bm[j], acc[0][j]);
        acc[1][j] = fmaf(a2.y, bm[j], acc[1][j]);
      }
    }
  }
  // reduce dsum across the 8 lanes sharing a row (low 3 bits of tid)
  dsum += __shfl_xor(dsum, 1, 64);
  dsum += __shfl_xor(dsum, 2, 64);
  dsum += __shfl_xor(dsum, 4, 64);
  if ((tid & 7) == 0) dn[arow] = dsum;
  __syncthreads();
  float inv0 = fast_rcp(dn[ty * 2]);
  float inv1 = fast_rcp(dn[ty * 2 + 1]);
  float* pO = out + ((size_t)b * CNR + r0 + ty * 2) * CD + d0 + tx * 4;
  float4 o0 = {acc[0][0] * inv0, acc[0][1] * inv0, acc[0][2] * inv0, acc[0][3] * inv0};
  float4 o1 = {acc[1][0] * inv1, acc[1][1] * inv1, acc[1][2] * inv1, acc[1][3] * inv1};
  *(float4*)(pO) = o0;
  *(float4*)(pO + CD) = o1;
}

extern "C" void kernel_launch(void* const* d_in, const int* in_sizes, int n_in,
                              void* d_out, int out_size, void* d_ws, size_t ws_size,
                              hipStream_t stream) {
  const float* X     = (const float*)d_in[0];
  const float* ref   = (const float*)d_in[1];
  const float* W_X   = (const float*)d_in[2];
  const float* b_X   = (const float*)d_in[3];
  const float* W_ref = (const float*)d_in[4];
  const float* b_ref = (const float*)d_in[5];
  const float* v_w   = (const float*)d_in[6];
  float* out = (float*)d_out;
  float* ws  = (float*)d_ws;

  float* exT = ws;                       // [B][H][NX] = 1,048,576 floats
  float* erT = ws + 1048576;             // [B][H][NR] = 1,048,576 floats
  float* eT  = ws + 2097152;             // [B][NR][NX] = 2,097,152 floats

  proj_fused<<<dim3(64, 4, 2), 256, 0, stream>>>(X, ref, W_X, W_ref, b_X, b_ref, exT, erT);
  scores_kernel<<<dim3(8, 16, 8), 256, 0, stream>>>(exT, erT, v_w, eT);
  wsum_fused<<<dim3(16, 4, 8), 256, 0, stream>>>(eT, X, out);
}

// Round 6
// 173.083 us; speedup vs baseline: 1.0187x; 1.0187x over previous
//
#include <hip/hip_runtime.h>
#include <math.h>

#define CB 8
#define CNX 512
#define CNR 512
#define CD 256
#define CH 256

__device__ __forceinline__ float fast_rcp(float x) {
#if __has_builtin(__builtin_amdgcn_rcpf)
  return __builtin_amdgcn_rcpf(x);
#else
  return 1.0f / x;
#endif
}
__device__ __forceinline__ float fast_exp2(float x) {
#if __has_builtin(__builtin_amdgcn_exp2f)
  return __builtin_amdgcn_exp2f(x);
#else
  return exp2f(x);
#endif
}

// Fused projections: z=0 -> exp(2*(X@W_X^T+b_X))^T, z=1 -> same for ref.
// ET[b][h][x] = exp2(K2L*(sum_k A[m][k]*W[h][k] + bias[h])), m=b*512+x
// 64(m) x 64(h) tile, K-tile 16, grid (64,4,2), block 256, 4x4 microtile.
// Register-prefetch pipeline: next K-tile's global loads issued before the
// compute loop so vmcnt drains during compute, not at the barrier.
__global__ __launch_bounds__(256) void proj_fused(
    const float* __restrict__ A0, const float* __restrict__ A1,
    const float* __restrict__ W0, const float* __restrict__ W1,
    const float* __restrict__ bias0, const float* __restrict__ bias1,
    float* __restrict__ E0, float* __restrict__ E1) {
  __shared__ float As[16][68];  // [k][m] padded
  __shared__ float Ws[16][68];  // [k][h] padded
  const int K = CD;
  int z = blockIdx.z;
  const float* A = z ? A1 : A0;
  const float* W = z ? W1 : W0;
  const float* bias = z ? bias1 : bias0;
  float* ET = z ? E1 : E0;
  int m0 = blockIdx.x * 64, n0 = blockIdx.y * 64;
  int tid = threadIdx.x;
  int tx = tid & 15, ty = tid >> 4;  // tx -> h, ty -> m(x)
  int lrow = tid >> 2, lc4 = tid & 3;
  float acc[4][4] = {};
  const float* pA = A + (size_t)(m0 + lrow) * K + lc4 * 4;
  const float* pW = W + (size_t)(n0 + lrow) * K + lc4 * 4;
  float4 av = *(const float4*)(pA);
  float4 wv = *(const float4*)(pW);
  for (int kt = 0; kt < K; kt += 16) {
    if (kt) __syncthreads();
    As[lc4 * 4 + 0][lrow] = av.x;
    As[lc4 * 4 + 1][lrow] = av.y;
    As[lc4 * 4 + 2][lrow] = av.z;
    As[lc4 * 4 + 3][lrow] = av.w;
    Ws[lc4 * 4 + 0][lrow] = wv.x;
    Ws[lc4 * 4 + 1][lrow] = wv.y;
    Ws[lc4 * 4 + 2][lrow] = wv.z;
    Ws[lc4 * 4 + 3][lrow] = wv.w;
    __syncthreads();
    if (kt + 16 < K) {
      av = *(const float4*)(pA + kt + 16);
      wv = *(const float4*)(pW + kt + 16);
    }
#pragma unroll
    for (int k = 0; k < 16; k++) {
      float4 a4 = *(const float4*)&As[k][ty * 4];
      float4 w4 = *(const float4*)&Ws[k][tx * 4];
      float am[4] = {a4.x, a4.y, a4.z, a4.w};
      float wm[4] = {w4.x, w4.y, w4.z, w4.w};
#pragma unroll
      for (int i = 0; i < 4; i++)
#pragma unroll
        for (int j = 0; j < 4; j++)
          acc[i][j] = fmaf(am[i], wm[j], acc[i][j]);
    }
  }
  const float K2L = 2.8853900817779268f;  // 2*log2(e)
  float4 bv = *(const float4*)(bias + n0 + tx * 4);
  float bm[4] = {bv.x, bv.y, bv.z, bv.w};
  int b = m0 >> 9;
  int xbase = (m0 & 511) + ty * 4;
#pragma unroll
  for (int j = 0; j < 4; j++) {
    int h = n0 + tx * 4 + j;
    float4 o = {fast_exp2(K2L * (acc[0][j] + bm[j])),
                fast_exp2(K2L * (acc[1][j] + bm[j])),
                fast_exp2(K2L * (acc[2][j] + bm[j])),
                fast_exp2(K2L * (acc[3][j] + bm[j]))};
    *(float4*)(ET + ((size_t)b * CH + h) * CNX + xbase) = o;
  }
}

// eT[b][r][x] = exp(-2 * sum_h v_w[h] / (exT[b][h][x]*erT[b][h][r] + 1))
// (unnormalized attention weight; softmax constant drops, normalization
//  happens in wsum_fused)
// 4-way h-merge; 64(x) x 32(r) tile, grid (8,16,8)=1024, block 256
// microtile: tx->x (4), ty->r (2); b128 x-fragment reads.
// Register-prefetch pipeline over 64-h chunks.
__global__ __launch_bounds__(256) void scores_kernel(
    const float* __restrict__ exT, const float* __restrict__ erT,
    const float* __restrict__ v_w, float* __restrict__ eT) {
  __shared__ float xs[64][64];  // [h][x] 16 KB
  __shared__ float rs[64][32];  // [h][r] 8 KB
  __shared__ float vsh[CH];
  int b = blockIdx.z;
  int x0 = blockIdx.x * 64, r0 = blockIdx.y * 32;
  int tid = threadIdx.x;
  int tx = tid & 15, ty = tid >> 4;
  vsh[tid] = v_w[tid];
  float acc[2][4] = {};
  const float* pX = exT + (size_t)b * CH * CNX + x0;
  const float* pR = erT + (size_t)b * CH * CNR + r0;
  int xrow = tid >> 4, xc4 = tid & 15;  // 16 h-rows x 16 float4 per pass
  int rrow = tid >> 3, rc4 = tid & 7;   // 32 h-rows x 8 float4 per pass
  float4 xv[4], rv[2];
#pragma unroll
  for (int p = 0; p < 4; p++)
    xv[p] = *(const float4*)(pX + (size_t)(xrow + p * 16) * CNX + xc4 * 4);
#pragma unroll
  for (int p = 0; p < 2; p++)
    rv[p] = *(const float4*)(pR + (size_t)(rrow + p * 32) * CNR + rc4 * 4);
  for (int hc = 0; hc < CH; hc += 64) {
    if (hc) __syncthreads();
#pragma unroll
    for (int p = 0; p < 4; p++)
      *(float4*)&xs[xrow + p * 16][xc4 * 4] = xv[p];
#pragma unroll
    for (int p = 0; p < 2; p++)
      *(float4*)&rs[rrow + p * 32][rc4 * 4] = rv[p];
    __syncthreads();
    if (hc + 64 < CH) {
#pragma unroll
      for (int p = 0; p < 4; p++)
        xv[p] = *(const float4*)(pX + (size_t)(hc + 64 + xrow + p * 16) * CNX + xc4 * 4);
#pragma unroll
      for (int p = 0; p < 2; p++)
        rv[p] = *(const float4*)(pR + (size_t)(hc + 64 + rrow + p * 32) * CNR + rc4 * 4);
    }
#pragma unroll 4
    for (int hq = 0; hq < 16; hq++) {
      int h0 = hq * 4;
      float4 vv = *(const float4*)&vsh[hc + h0];
      float4 xa = *(const float4*)&xs[h0 + 0][tx * 4];
      float4 xb = *(const float4*)&xs[h0 + 1][tx * 4];
      float4 xc = *(const float4*)&xs[h0 + 2][tx * 4];
      float4 xd = *(const float4*)&xs[h0 + 3][tx * 4];
      float2 ra = *(const float2*)&rs[h0 + 0][ty * 2];
      float2 rb = *(const float2*)&rs[h0 + 1][ty * 2];
      float2 rc = *(const float2*)&rs[h0 + 2][ty * 2];
      float2 rd = *(const float2*)&rs[h0 + 3][ty * 2];
      float xam[4] = {xa.x, xa.y, xa.z, xa.w};
      float xbm[4] = {xb.x, xb.y, xb.z, xb.w};
      float xcm[4] = {xc.x, xc.y, xc.z, xc.w};
      float xdm[4] = {xd.x, xd.y, xd.z, xd.w};
      float ram[2] = {ra.x, ra.y};
      float rbm[2] = {rb.x, rb.y};
      float rcm[2] = {rc.x, rc.y};
      float rdm[2] = {rd.x, rd.y};
#pragma unroll
      for (int i = 0; i < 2; i++)
#pragma unroll
        for (int j = 0; j < 4; j++) {
          float a = fmaf(ram[i], xam[j], 1.0f);
          float bb = fmaf(rbm[i], xbm[j], 1.0f);
          float c = fmaf(rcm[i], xcm[j], 1.0f);
          float d = fmaf(rdm[i], xdm[j], 1.0f);
          float q12 = a * bb, q34 = c * d;
          float p12 = fmaf(vv.y, a, vv.x * bb);
          float p34 = fmaf(vv.w, c, vv.z * d);
          float num = fmaf(p34, q12, p12 * q34);
          acc[i][j] = fmaf(num, fast_rcp(q12 * q34), acc[i][j]);
        }
    }
  }
  // e = exp(-2 * acc); exp2 with fused scale
  const float NL2E = -2.0f * 1.4426950408889634f;
  float* pO = eT + ((size_t)b * CNR + r0 + ty * 2) * CNX + x0 + tx * 4;
#pragma unroll
  for (int i = 0; i < 2; i++) {
    float4 o = {fast_exp2(acc[i][0] * NL2E), fast_exp2(acc[i][1] * NL2E),
                fast_exp2(acc[i][2] * NL2E), fast_exp2(acc[i][3] * NL2E)};
    *(float4*)(pO + (size_t)i * CNX) = o;
  }
}

// Normalized weighted sum from unnormalized weights eT:
// out[b][r][d] = sum_x eT[b][r][x]*X[b][x][d] / sum_x eT[b][r][x]
// 32(r) x 64(d) tile, K-tile 32, grid (16,4,8)=512 blocks.
// Register-prefetch pipeline over 32-k chunks.
__global__ __launch_bounds__(256) void wsum_fused(
    const float* __restrict__ eT, const float* __restrict__ X,
    float* __restrict__ out) {
  __shared__ float As[32][34];  // [k][r] unnormalized attn (even pad for b64)
  __shared__ float Bs[32][68];  // [k][d]
  __shared__ float dn[32];
  int b = blockIdx.z;
  int r0 = blockIdx.x * 32, d0 = blockIdx.y * 64;
  int tid = threadIdx.x;
  int tx = tid & 15, ty = tid >> 4;    // tx -> d(4), ty -> r(2)
  int arow = tid >> 3, ak4 = tid & 7;  // eT: 32 r-rows x 8 float4
  int brow = tid >> 4, bc4 = tid & 15; // X: 16 x-rows x 64 d (2 passes)
  float acc[2][4] = {};
  float dsum = 0.0f;
  const float* pE = eT + ((size_t)b * CNR + r0 + arow) * CNX + ak4 * 4;
  const float* pB = X + ((size_t)b * CNX + brow) * CD + d0 + bc4 * 4;
  float4 ev = *(const float4*)(pE);
  float4 bv0 = *(const float4*)(pB);
  float4 bv1 = *(const float4*)(pB + (size_t)16 * CD);
  for (int kt = 0; kt < CNX; kt += 32) {
    if (kt) __syncthreads();
    dsum += (ev.x + ev.y) + (ev.z + ev.w);
    As[ak4 * 4 + 0][arow] = ev.x;
    As[ak4 * 4 + 1][arow] = ev.y;
    As[ak4 * 4 + 2][arow] = ev.z;
    As[ak4 * 4 + 3][arow] = ev.w;
    *(float4*)&Bs[brow][bc4 * 4] = bv0;
    *(float4*)&Bs[brow + 16][bc4 * 4] = bv1;
    __syncthreads();
    if (kt + 32 < CNX) {
      ev = *(const float4*)(pE + kt + 32);
      bv0 = *(const float4*)(pB + (size_t)(kt + 32) * CD);
      bv1 = *(const float4*)(pB + (size_t)(kt + 48) * CD);
    }
#pragma unroll 8
    for (int k = 0; k < 32; k++) {
      float2 a2 = *(const float2*)&As[k][ty * 2];
      float4 b4 = *(const float4*)&Bs[k][tx * 4];
      float bm[4] = {b4.x, b4.y, b4.z, b4.w};
#pragma unroll
      for (int j = 0; j < 4; j++) {
        acc[0][j] = fmaf(a2.x, bm[j], acc[0][j]);
        acc[1][j] = fmaf(a2.y, bm[j], acc[1][j]);
      }
    }
  }
  // reduce dsum across the 8 lanes sharing a row (low 3 bits of tid)
  dsum += __shfl_xor(dsum, 1, 64);
  dsum += __shfl_xor(dsum, 2, 64);
  dsum += __shfl_xor(dsum, 4, 64);
  if ((tid & 7) == 0) dn[arow] = dsum;
  __syncthreads();
  float inv0 = fast_rcp(dn[ty * 2]);
  float inv1 = fast_rcp(dn[ty * 2 + 1]);
  float* pO = out + ((size_t)b * CNR + r0 + ty * 2) * CD + d0 + tx * 4;
  float4 o0 = {acc[0][0] * inv0, acc[0][1] * inv0, acc[0][2] * inv0, acc[0][3] * inv0};
  float4 o1 = {acc[1][0] * inv1, acc[1][1] * inv1, acc[1][2] * inv1, acc[1][3] * inv1};
  *(float4*)(pO) = o0;
  *(float4*)(pO + CD) = o1;
}

extern "C" void kernel_launch(void* const* d_in, const int* in_sizes, int n_in,
                              void* d_out, int out_size, void* d_ws, size_t ws_size,
                              hipStream_t stream) {
  const float* X     = (const float*)d_in[0];
  const float* ref   = (const float*)d_in[1];
  const float* W_X   = (const float*)d_in[2];
  const float* b_X   = (const float*)d_in[3];
  const float* W_ref = (const float*)d_in[4];
  const float* b_ref = (const float*)d_in[5];
  const float* v_w   = (const float*)d_in[6];
  float* out = (float*)d_out;
  float* ws  = (float*)d_ws;

  float* exT = ws;                       // [B][H][NX] = 1,048,576 floats
  float* erT = ws + 1048576;             // [B][H][NR] = 1,048,576 floats
  float* eT  = ws + 2097152;             // [B][NR][NX] = 2,097,152 floats

  proj_fused<<<dim3(64, 4, 2), 256, 0, stream>>>(X, ref, W_X, W_ref, b_X, b_ref, exT, erT);
  scores_kernel<<<dim3(8, 16, 8), 256, 0, stream>>>(exT, erT, v_w, eT);
  wsum_fused<<<dim3(16, 4, 8), 256, 0, stream>>>(eT, X, out);
}

// Round 7
// 168.414 us; speedup vs baseline: 1.0470x; 1.0277x over previous
//
#include <hip/hip_runtime.h>
#include <math.h>

#define CB 8
#define CNX 512
#define CNR 512
#define CD 256
#define CH 256

__device__ __forceinline__ float fast_rcp(float x) {
#if __has_builtin(__builtin_amdgcn_rcpf)
  return __builtin_amdgcn_rcpf(x);
#else
  return 1.0f / x;
#endif
}
__device__ __forceinline__ float fast_exp2(float x) {
#if __has_builtin(__builtin_amdgcn_exp2f)
  return __builtin_amdgcn_exp2f(x);
#else
  return exp2f(x);
#endif
}

// Fused projections: z=0 -> exp(2*(X@W_X^T+b_X))^T, z=1 -> same for ref.
// ET[b][h][x] = exp2(K2L*(sum_k A[m][k]*W[h][k] + bias[h])), m=b*512+x
// 64(m) x 64(h) tile, K-tile 16, grid (64,4,2), block 256, 4x4 microtile.
__global__ __launch_bounds__(256) void proj_fused(
    const float* __restrict__ A0, const float* __restrict__ A1,
    const float* __restrict__ W0, const float* __restrict__ W1,
    const float* __restrict__ bias0, const float* __restrict__ bias1,
    float* __restrict__ E0, float* __restrict__ E1) {
  __shared__ float As[16][68];  // [k][m] padded
  __shared__ float Ws[16][68];  // [k][h] padded
  const int K = CD;
  int z = blockIdx.z;
  const float* A = z ? A1 : A0;
  const float* W = z ? W1 : W0;
  const float* bias = z ? bias1 : bias0;
  float* ET = z ? E1 : E0;
  int m0 = blockIdx.x * 64, n0 = blockIdx.y * 64;
  int tid = threadIdx.x;
  int tx = tid & 15, ty = tid >> 4;  // tx -> h, ty -> m(x)
  int lrow = tid >> 2, lc4 = tid & 3;
  float acc[4][4] = {};
  const float* pA = A + (size_t)(m0 + lrow) * K + lc4 * 4;
  const float* pW = W + (size_t)(n0 + lrow) * K + lc4 * 4;
  float4 av = *(const float4*)(pA);
  float4 wv = *(const float4*)(pW);
  for (int kt = 0; kt < K; kt += 16) {
    if (kt) __syncthreads();
    As[lc4 * 4 + 0][lrow] = av.x;
    As[lc4 * 4 + 1][lrow] = av.y;
    As[lc4 * 4 + 2][lrow] = av.z;
    As[lc4 * 4 + 3][lrow] = av.w;
    Ws[lc4 * 4 + 0][lrow] = wv.x;
    Ws[lc4 * 4 + 1][lrow] = wv.y;
    Ws[lc4 * 4 + 2][lrow] = wv.z;
    Ws[lc4 * 4 + 3][lrow] = wv.w;
    __syncthreads();
    if (kt + 16 < K) {
      av = *(const float4*)(pA + kt + 16);
      wv = *(const float4*)(pW + kt + 16);
    }
#pragma unroll
    for (int k = 0; k < 16; k++) {
      float4 a4 = *(const float4*)&As[k][ty * 4];
      float4 w4 = *(const float4*)&Ws[k][tx * 4];
      float am[4] = {a4.x, a4.y, a4.z, a4.w};
      float wm[4] = {w4.x, w4.y, w4.z, w4.w};
#pragma unroll
      for (int i = 0; i < 4; i++)
#pragma unroll
        for (int j = 0; j < 4; j++)
          acc[i][j] = fmaf(am[i], wm[j], acc[i][j]);
    }
  }
  const float K2L = 2.8853900817779268f;  // 2*log2(e)
  float4 bv = *(const float4*)(bias + n0 + tx * 4);
  float bm[4] = {bv.x, bv.y, bv.z, bv.w};
  int b = m0 >> 9;
  int xbase = (m0 & 511) + ty * 4;
#pragma unroll
  for (int j = 0; j < 4; j++) {
    int h = n0 + tx * 4 + j;
    float4 o = {fast_exp2(K2L * (acc[0][j] + bm[j])),
                fast_exp2(K2L * (acc[1][j] + bm[j])),
                fast_exp2(K2L * (acc[2][j] + bm[j])),
                fast_exp2(K2L * (acc[3][j] + bm[j]))};
    *(float4*)(ET + ((size_t)b * CH + h) * CNX + xbase) = o;
  }
}

// eT[b][r][x] = exp(-2 * sum_h v_w[h] / (exT[b][h][x]*erT[b][h][r] + 1))
// 4-way h-merge; 64(x) x 64(r) tile, grid (8,8,8)=512, block 256
// microtile: tx->x (4), ty->r (4) — 16 elems/thread so the LDS pipe
// (1 per CU, shared by all resident waves) carries half the bytes/elem.
__global__ __launch_bounds__(256) void scores_kernel(
    const float* __restrict__ exT, const float* __restrict__ erT,
    const float* __restrict__ v_w, float* __restrict__ eT) {
  __shared__ float xs[64][64];  // [h][x] 16 KB
  __shared__ float rs[64][64];  // [h][r] 16 KB
  __shared__ float vsh[CH];
  int b = blockIdx.z;
  int x0 = blockIdx.x * 64, r0 = blockIdx.y * 64;
  int tid = threadIdx.x;
  int tx = tid & 15, ty = tid >> 4;
  vsh[tid] = v_w[tid];
  float acc[4][4] = {};
  const float* pX = exT + (size_t)b * CH * CNX + x0;
  const float* pR = erT + (size_t)b * CH * CNR + r0;
  int srow = tid >> 4, sc4 = tid & 15;  // 16 h-rows x 16 float4 per pass
  float4 xv[4], rv[4];
#pragma unroll
  for (int p = 0; p < 4; p++) {
    xv[p] = *(const float4*)(pX + (size_t)(srow + p * 16) * CNX + sc4 * 4);
    rv[p] = *(const float4*)(pR + (size_t)(srow + p * 16) * CNR + sc4 * 4);
  }
  for (int hc = 0; hc < CH; hc += 64) {
    if (hc) __syncthreads();
#pragma unroll
    for (int p = 0; p < 4; p++) {
      *(float4*)&xs[srow + p * 16][sc4 * 4] = xv[p];
      *(float4*)&rs[srow + p * 16][sc4 * 4] = rv[p];
    }
    __syncthreads();
    if (hc + 64 < CH) {
#pragma unroll
      for (int p = 0; p < 4; p++) {
        xv[p] = *(const float4*)(pX + (size_t)(hc + 64 + srow + p * 16) * CNX + sc4 * 4);
        rv[p] = *(const float4*)(pR + (size_t)(hc + 64 + srow + p * 16) * CNR + sc4 * 4);
      }
    }
#pragma unroll 2
    for (int hq = 0; hq < 16; hq++) {
      int h0 = hq * 4;
      float4 vv = *(const float4*)&vsh[hc + h0];
      float4 xa = *(const float4*)&xs[h0 + 0][tx * 4];
      float4 xb = *(const float4*)&xs[h0 + 1][tx * 4];
      float4 xc = *(const float4*)&xs[h0 + 2][tx * 4];
      float4 xd = *(const float4*)&xs[h0 + 3][tx * 4];
      float4 ra = *(const float4*)&rs[h0 + 0][ty * 4];
      float4 rb = *(const float4*)&rs[h0 + 1][ty * 4];
      float4 rc = *(const float4*)&rs[h0 + 2][ty * 4];
      float4 rd = *(const float4*)&rs[h0 + 3][ty * 4];
      float xam[4] = {xa.x, xa.y, xa.z, xa.w};
      float xbm[4] = {xb.x, xb.y, xb.z, xb.w};
      float xcm[4] = {xc.x, xc.y, xc.z, xc.w};
      float xdm[4] = {xd.x, xd.y, xd.z, xd.w};
      float ram[4] = {ra.x, ra.y, ra.z, ra.w};
      float rbm[4] = {rb.x, rb.y, rb.z, rb.w};
      float rcm[4] = {rc.x, rc.y, rc.z, rc.w};
      float rdm[4] = {rd.x, rd.y, rd.z, rd.w};
#pragma unroll
      for (int i = 0; i < 4; i++)
#pragma unroll
        for (int j = 0; j < 4; j++) {
          float a = fmaf(ram[i], xam[j], 1.0f);
          float bb = fmaf(rbm[i], xbm[j], 1.0f);
          float c = fmaf(rcm[i], xcm[j], 1.0f);
          float d = fmaf(rdm[i], xdm[j], 1.0f);
          float q12 = a * bb, q34 = c * d;
          float p12 = fmaf(vv.y, a, vv.x * bb);
          float p34 = fmaf(vv.w, c, vv.z * d);
          float num = fmaf(p34, q12, p12 * q34);
          acc[i][j] = fmaf(num, fast_rcp(q12 * q34), acc[i][j]);
        }
    }
  }
  // e = exp(-2 * acc); exp2 with fused scale
  const float NL2E = -2.0f * 1.4426950408889634f;
  float* pO = eT + ((size_t)b * CNR + r0 + ty * 4) * CNX + x0 + tx * 4;
#pragma unroll
  for (int i = 0; i < 4; i++) {
    float4 o = {fast_exp2(acc[i][0] * NL2E), fast_exp2(acc[i][1] * NL2E),
                fast_exp2(acc[i][2] * NL2E), fast_exp2(acc[i][3] * NL2E)};
    *(float4*)(pO + (size_t)i * CNX) = o;
  }
}

// Normalized weighted sum from unnormalized weights eT:
// out[b][r][d] = sum_x eT[b][r][x]*X[b][x][d] / sum_x eT[b][r][x]
// 32(r) x 64(d) tile, K-tile 32, grid (16,4,8)=512 blocks.
__global__ __launch_bounds__(256) void wsum_fused(
    const float* __restrict__ eT, const float* __restrict__ X,
    float* __restrict__ out) {
  __shared__ float As[32][34];  // [k][r] unnormalized attn (even pad for b64)
  __shared__ float Bs[32][68];  // [k][d]
  __shared__ float dn[32];
  int b = blockIdx.z;
  int r0 = blockIdx.x * 32, d0 = blockIdx.y * 64;
  int tid = threadIdx.x;
  int tx = tid & 15, ty = tid >> 4;    // tx -> d(4), ty -> r(2)
  int arow = tid >> 3, ak4 = tid & 7;  // eT: 32 r-rows x 8 float4
  int brow = tid >> 4, bc4 = tid & 15; // X: 16 x-rows x 64 d (2 passes)
  float acc[2][4] = {};
  float dsum = 0.0f;
  const float* pE = eT + ((size_t)b * CNR + r0 + arow) * CNX + ak4 * 4;
  const float* pB = X + ((size_t)b * CNX + brow) * CD + d0 + bc4 * 4;
  float4 ev = *(const float4*)(pE);
  float4 bv0 = *(const float4*)(pB);
  float4 bv1 = *(const float4*)(pB + (size_t)16 * CD);
  for (int kt = 0; kt < CNX; kt += 32) {
    if (kt) __syncthreads();
    dsum += (ev.x + ev.y) + (ev.z + ev.w);
    As[ak4 * 4 + 0][arow] = ev.x;
    As[ak4 * 4 + 1][arow] = ev.y;
    As[ak4 * 4 + 2][arow] = ev.z;
    As[ak4 * 4 + 3][arow] = ev.w;
    *(float4*)&Bs[brow][bc4 * 4] = bv0;
    *(float4*)&Bs[brow + 16][bc4 * 4] = bv1;
    __syncthreads();
    if (kt + 32 < CNX) {
      ev = *(const float4*)(pE + kt + 32);
      bv0 = *(const float4*)(pB + (size_t)(kt + 32) * CD);
      bv1 = *(const float4*)(pB + (size_t)(kt + 48) * CD);
    }
#pragma unroll 8
    for (int k = 0; k < 32; k++) {
      float2 a2 = *(const float2*)&As[k][ty * 2];
      float4 b4 = *(const float4*)&Bs[k][tx * 4];
      float bm[4] = {b4.x, b4.y, b4.z, b4.w};
#pragma unroll
      for (int j = 0; j < 4; j++) {
        acc[0][j] = fmaf(a2.x, bm[j], acc[0][j]);
        acc[1][j] = fmaf(a2.y, bm[j], acc[1][j]);
      }
    }
  }
  // reduce dsum across the 8 lanes sharing a row (low 3 bits of tid)
  dsum += __shfl_xor(dsum, 1, 64);
  dsum += __shfl_xor(dsum, 2, 64);
  dsum += __shfl_xor(dsum, 4, 64);
  if ((tid & 7) == 0) dn[arow] = dsum;
  __syncthreads();
  float inv0 = fast_rcp(dn[ty * 2]);
  float inv1 = fast_rcp(dn[ty * 2 + 1]);
  float* pO = out + ((size_t)b * CNR + r0 + ty * 2) * CD + d0 + tx * 4;
  float4 o0 = {acc[0][0] * inv0, acc[0][1] * inv0, acc[0][2] * inv0, acc[0][3] * inv0};
  float4 o1 = {acc[1][0] * inv1, acc[1][1] * inv1, acc[1][2] * inv1, acc[1][3] * inv1};
  *(float4*)(pO) = o0;
  *(float4*)(pO + CD) = o1;
}

extern "C" void kernel_launch(void* const* d_in, const int* in_sizes, int n_in,
                              void* d_out, int out_size, void* d_ws, size_t ws_size,
                              hipStream_t stream) {
  const float* X     = (const float*)d_in[0];
  const float* ref   = (const float*)d_in[1];
  const float* W_X   = (const float*)d_in[2];
  const float* b_X   = (const float*)d_in[3];
  const float* W_ref = (const float*)d_in[4];
  const float* b_ref = (const float*)d_in[5];
  const float* v_w   = (const float*)d_in[6];
  float* out = (float*)d_out;
  float* ws  = (float*)d_ws;

  float* exT = ws;                       // [B][H][NX] = 1,048,576 floats
  float* erT = ws + 1048576;             // [B][H][NR] = 1,048,576 floats
  float* eT  = ws + 2097152;             // [B][NR][NX] = 2,097,152 floats

  proj_fused<<<dim3(64, 4, 2), 256, 0, stream>>>(X, ref, W_X, W_ref, b_X, b_ref, exT, erT);
  scores_kernel<<<dim3(8, 8, 8), 256, 0, stream>>>(exT, erT, v_w, eT);
  wsum_fused<<<dim3(16, 4, 8), 256, 0, stream>>>(eT, X, out);
}